// Round 6
// baseline (255.642 us; speedup 1.0000x reference)
//
#include <hip/hip_runtime.h>
#include <hip/hip_cooperative_groups.h>
namespace cg = cooperative_groups;

#define BB 256
#define SS 2048
#define FF 64
#define NBB 32

#define PL 64             // output timesteps per scan partition
#define NP (SS/PL)        // 32 partitions
#define WUP 384           // speculative warm-up steps (forgetting ~e^-300)
#define NBLK 1024         // cooperative grid (4 blocks/CU, co-resident)

// 2*log2(e): folded into u so the scan's tanh needs only exp2 on the chain
#define TWO_OVER_LN2 2.885390081777927f

// ---------------------------------------------------------------------------
// One cooperative kernel, 3 phases, 2 grid syncs (replaces 3 kernel launches;
// round-5 accounting showed ~15us of inter-kernel gap overhead).
//  phase 1 (all 1024 blocks): u4/tf4 projection. 4 rows (same b, one t-quad)
//          per 16-lane group per iter -> 4 loads in flight/wave (HBM sat.)
//          and one float4 store each to u4/tf4.
//  phase 2 (blocks 0..31): speculative blocked scan (identical to round 5).
//  phase 3 (blocks 0..511): intensity head, 4 t per block.
// t4 layout: elem (b,t) at ((t>>2)*BB + b)*4 + (t&3).
// ---------------------------------------------------------------------------
__global__ __launch_bounds__(256, 4) void k_coop(
    const float* __restrict__ X, const float* __restrict__ W_ih,
    const float* __restrict__ b_ih, const float* __restrict__ b_hh,
    const float* __restrict__ W_hh, const float* __restrict__ hx0,
    const float* __restrict__ W_h2p, const float* __restrict__ b_h2p,
    float* __restrict__ u4, float* __restrict__ tf4,
    float* __restrict__ out_h, float* __restrict__ out_l)
{
    cg::grid_group grid = cg::this_grid();
    __shared__ float4 cb[NBB];

    // ---------------- phase 1: projection ----------------
    {
        const int l = threadIdx.x & 15;
        const int group  = (blockIdx.x * blockDim.x + threadIdx.x) >> 4;
        const int ngroups = (NBLK * 256) >> 4;               // 16384
        const float4 w = reinterpret_cast<const float4*>(W_ih)[l];
        const float bias = b_ih[0] + b_hh[0];
        const float wp = W_hh[0] * TWO_OVER_LN2;
        #pragma unroll 1
        for (int it = 0; it < (BB * SS) / (16384 * 4); ++it) {   // 8 iters
            const int r0 = (it * 16384 + group) * 4;   // 4 rows: same b, t-quad
            float4 v[4];
            #pragma unroll
            for (int k = 0; k < 4; ++k)
                v[k] = reinterpret_cast<const float4*>(X + (size_t)(r0 + k) * FF)[l];
            float pq[4];
            #pragma unroll
            for (int k = 0; k < 4; ++k) {
                float p = v[k].x*w.x + v[k].y*w.y + v[k].z*w.z + v[k].w*w.w;
                p += __shfl_xor(p, 1);
                p += __shfl_xor(p, 2);
                p += __shfl_xor(p, 4);
                p += __shfl_xor(p, 8);
                pq[k] = TWO_OVER_LN2 * (p + bias) + wp;
            }
            if (l == 0) {
                const int b = r0 >> 11;                    // r0 / SS
                const int t = r0 & (SS - 1);               // multiple of 4
                const size_t qi = (size_t)(t >> 2) * BB + b;
                reinterpret_cast<float4*>(u4)[qi] =
                    make_float4(pq[0], pq[1], pq[2], pq[3]);
                reinterpret_cast<float4*>(tf4)[qi] =
                    make_float4(v[0].y, v[1].y, v[2].y, v[3].y);
            }
        }
    }
    grid.sync();

    // ---------------- phase 2: speculative blocked scan ----------------
    if (blockIdx.x < NP) {
        const int b = threadIdx.x;
        const int p = blockIdx.x;
        const float m2w = -2.0f * (W_hh[0] * TWO_OVER_LN2);

        int t_s = p * PL - WUP;
        float r;
        if (t_s <= 0) { t_s = 0; r = 0.5f * (1.0f - hx0[b]); }   // exact start
        else          { r = 0.5f; }                               // neutral

        const float4* U = reinterpret_cast<const float4*>(u4);
        const int q0   = t_s >> 2;
        const int q1   = ((p + 1) * PL) >> 2;     // q1-q0 multiple of 8
        const int qout = (p * PL) >> 2;

        float4 buf[8];
        #pragma unroll
        for (int i = 0; i < 8; ++i) {
            int q = q0 + i; if (q > q1 - 1) q = q1 - 1;
            buf[i] = U[(size_t)q * BB + b];
        }
        #pragma unroll 1
        for (int q = q0; q < q1; q += 8) {
            #pragma unroll
            for (int i = 0; i < 8; ++i) {
                const int qq = q + i;
                const float4 c = buf[i];
                float z0 = fmaf(m2w, r, c.x);
                r = __builtin_amdgcn_rcpf(__builtin_amdgcn_exp2f(z0) + 1.0f);
                if (qq >= qout) out_h[(size_t)(qq*4+0)*BB + b] = fmaf(-2.0f, r, 1.0f);
                float z1 = fmaf(m2w, r, c.y);
                r = __builtin_amdgcn_rcpf(__builtin_amdgcn_exp2f(z1) + 1.0f);
                if (qq >= qout) out_h[(size_t)(qq*4+1)*BB + b] = fmaf(-2.0f, r, 1.0f);
                float z2 = fmaf(m2w, r, c.z);
                r = __builtin_amdgcn_rcpf(__builtin_amdgcn_exp2f(z2) + 1.0f);
                if (qq >= qout) out_h[(size_t)(qq*4+2)*BB + b] = fmaf(-2.0f, r, 1.0f);
                float z3 = fmaf(m2w, r, c.w);
                r = __builtin_amdgcn_rcpf(__builtin_amdgcn_exp2f(z3) + 1.0f);
                if (qq >= qout) out_h[(size_t)(qq*4+3)*BB + b] = fmaf(-2.0f, r, 1.0f);
                int qn = qq + 8; if (qn > q1 - 1) qn = q1 - 1;    // refill
                buf[i] = U[(size_t)qn * BB + b];
            }
        }
    }
    grid.sync();

    // ---------------- phase 3: intensity head (blocks 0..511) ----------------
    if (blockIdx.x < (SS / 4)) {
        if (threadIdx.x < NBB) {
            int j = threadIdx.x;
            cb[j] = make_float4(W_h2p[2*j], W_h2p[2*j+1], b_h2p[2*j], b_h2p[2*j+1]);
        }
        __syncthreads();

        const int bi = threadIdx.x;
        const int t0 = blockIdx.x * 4;                 // multiple of 4

        float4 tq = reinterpret_cast<const float4*>(tf4)[(size_t)(t0 >> 2) * BB + bi];
        float tt[4] = {tq.x, tq.y, tq.z, tq.w};
        float hx[4], s[4] = {0.f, 0.f, 0.f, 0.f};
        #pragma unroll
        for (int k = 0; k < 4; ++k)
            hx[k] = out_h[(size_t)(t0 + k) * BB + bi];

        #pragma unroll 4
        for (int j = 0; j < NBB; ++j) {
            const float4 c = cb[j];
            #pragma unroll
            for (int k = 0; k < 4; ++k) {
                float alpha = fmaf(hx[k], c.x, c.z);
                float beta  = fmaf(hx[k], c.y, c.w);
                s[k] += fmaxf(fmaf(alpha, tt[k], beta), 0.0f);
            }
        }
        #pragma unroll
        for (int k = 0; k < 4; ++k) {
            float vv = s[k];
            float as = fabsf(vv);
            float e  = __builtin_amdgcn_exp2f(-as * 1.4426950408889634f);
            float lg = __builtin_amdgcn_logf(1.0f + e) * 0.6931471805599453f;
            out_l[(size_t)(t0 + k) * BB + bi] = fmaxf(vv, 0.0f) + lg;
        }
    }
}

// ---------------------------------------------------------------------------
extern "C" void kernel_launch(void* const* d_in, const int* in_sizes, int n_in,
                              void* d_out, int out_size, void* d_ws, size_t ws_size,
                              hipStream_t stream) {
    const float* X     = (const float*)d_in[0];
    const float* hx0   = (const float*)d_in[1];
    const float* W_ih  = (const float*)d_in[2];
    const float* b_ih  = (const float*)d_in[3];
    const float* W_hh  = (const float*)d_in[4];
    const float* b_hh  = (const float*)d_in[5];
    const float* W_h2p = (const float*)d_in[6];
    const float* b_h2p = (const float*)d_in[7];

    float* out_h = (float*)d_out;                 // hidden_states (S,B,1) [t][b]
    float* out_l = out_h + (size_t)SS * BB;       // intensity     (S,B)   [t][b]
    float* u4  = (float*)d_ws;                    // u'' t4-layout, 2 MiB
    float* tf4 = u4 + (size_t)BB * SS;            // X[:,:,1] t4-layout, 2 MiB

    void* args[] = { (void*)&X, (void*)&W_ih, (void*)&b_ih, (void*)&b_hh,
                     (void*)&W_hh, (void*)&hx0, (void*)&W_h2p, (void*)&b_h2p,
                     (void*)&u4, (void*)&tf4, (void*)&out_h, (void*)&out_l };
    hipLaunchCooperativeKernel((const void*)k_coop, dim3(NBLK), dim3(256),
                               args, 0, stream);
}

// Round 7
// 49.058 us; speedup vs baseline: 5.2110x; 5.2110x over previous
//
#include <hip/hip_runtime.h>

#define BB 256
#define SS 2048
#define FF 64
#define NBB 32

#define PL 32             // output timesteps per scan partition
#define NP (SS/PL)        // 64 partitions
#define WUP 352           // warm-up steps; 352+32=384 steps = 96 quads (mult. of 8);
                          // clamped partitions get (p+1)*8 quads (also mult. of 8)

// 2*log2(e): folded into u so the scan's tanh needs only exp2 on the chain
#define TWO_OVER_LN2 2.885390081777927f

// ---------------------------------------------------------------------------
// K1: u4[t4] = 2log2e*(dot(X[b,t,:],W_ih)+b_ih+b_hh) + 2log2e*W_hh
//     tf4[t4] = X[b,t,1]
// t4 layout: elem (b,t) at ((t>>2)*BB + b)*4 + (t&3) -> scan/lam read float4.
// ---------------------------------------------------------------------------
__global__ __launch_bounds__(256) void k_proj(
    const float* __restrict__ X, const float* __restrict__ W_ih,
    const float* __restrict__ b_ih, const float* __restrict__ b_hh,
    const float* __restrict__ W_hh,
    float* __restrict__ u4, float* __restrict__ tf4)
{
    const int l = threadIdx.x & 15;
    const int group  = (blockIdx.x * blockDim.x + threadIdx.x) >> 4;
    const int ngroups = (gridDim.x * blockDim.x) >> 4;
    const float4 w = reinterpret_cast<const float4*>(W_ih)[l];
    const float bias = b_ih[0] + b_hh[0];
    const float wp = W_hh[0] * TWO_OVER_LN2;
    const int nrows = BB * SS;
    for (int r = group; r < nrows; r += ngroups) {
        const float4 v = reinterpret_cast<const float4*>(X + (size_t)r * FF)[l];
        float p = v.x * w.x + v.y * w.y + v.z * w.z + v.w * w.w;
        p += __shfl_xor(p, 1);
        p += __shfl_xor(p, 2);
        p += __shfl_xor(p, 4);
        p += __shfl_xor(p, 8);
        if (l == 0) {
            const int b = r >> 11;          // r / SS
            const int t = r & (SS - 1);
            const int idx = ((t >> 2) * BB + b) * 4 + (t & 3);
            u4[idx]  = TWO_OVER_LN2 * (p + bias) + wp;
            tf4[idx] = v.y;
        }
    }
}

// ---------------------------------------------------------------------------
// K2: fused speculative scan + intensity head. block = partition p (64),
// thread = batch b. Warm-up iterations are branchless (no output); the FINAL
// 8-quad iteration is exactly the 32-t output window (PL=32 = one iteration),
// stashing hx in 32 static registers. Then the same thread runs the 32-basis
// head on its own hx values — no sync, no LDS handoff, no global hx re-read.
// ---------------------------------------------------------------------------
#define SSTEP(c) { \
    float z_ = fmaf(m2w, r, (c)); \
    r = __builtin_amdgcn_rcpf(__builtin_amdgcn_exp2f(z_) + 1.0f); }

#define WQUAD(i, base) { \
    const float4 c_ = buf[i]; \
    SSTEP(c_.x) SSTEP(c_.y) SSTEP(c_.z) SSTEP(c_.w) \
    buf[i] = U[(size_t)((base) + 8 + (i)) * BB + b]; }

#define OQUAD(i) { \
    const float4 c_ = buf[i]; \
    SSTEP(c_.x) hxr[(i)*4+0] = fmaf(-2.0f, r, 1.0f); \
    SSTEP(c_.y) hxr[(i)*4+1] = fmaf(-2.0f, r, 1.0f); \
    SSTEP(c_.z) hxr[(i)*4+2] = fmaf(-2.0f, r, 1.0f); \
    SSTEP(c_.w) hxr[(i)*4+3] = fmaf(-2.0f, r, 1.0f); \
    out_h[(size_t)(tb0 + (i)*4+0)*BB + b] = hxr[(i)*4+0]; \
    out_h[(size_t)(tb0 + (i)*4+1)*BB + b] = hxr[(i)*4+1]; \
    out_h[(size_t)(tb0 + (i)*4+2)*BB + b] = hxr[(i)*4+2]; \
    out_h[(size_t)(tb0 + (i)*4+3)*BB + b] = hxr[(i)*4+3]; }

__global__ __launch_bounds__(256) void k_scanlam(
    const float* __restrict__ u4, const float* __restrict__ tf4,
    const float* __restrict__ hx0, const float* __restrict__ W_hh,
    const float* __restrict__ W_h2p, const float* __restrict__ b_h2p,
    float* __restrict__ out_h, float* __restrict__ out_l)
{
    __shared__ float4 cb[NBB];
    if (threadIdx.x < NBB) {
        int j = threadIdx.x;
        cb[j] = make_float4(W_h2p[2*j], W_h2p[2*j+1], b_h2p[2*j], b_h2p[2*j+1]);
    }
    __syncthreads();

    const int b = threadIdx.x;
    const int p = blockIdx.x;
    const float m2w = -2.0f * (W_hh[0] * TWO_OVER_LN2);

    int t_s = p * PL - WUP;
    float r;
    if (t_s <= 0) { t_s = 0; r = 0.5f * (1.0f - hx0[b]); }   // exact start
    else          { r = 0.5f; }                               // neutral (hx=0)

    const float4* U  = reinterpret_cast<const float4*>(u4);
    const float4* TF = reinterpret_cast<const float4*>(tf4);
    const int q0   = t_s >> 2;
    const int q1   = (p + 1) * (PL/4);        // exclusive end quad
    const int qout = p * (PL/4);              // first output quad (= q1-8)
    const int tb0  = p * PL;                  // first output t
    const int nwu  = ((q1 - q0) >> 3) - 1;    // warm-up iterations (8 quads each)

    float4 buf[8];
    #pragma unroll
    for (int i = 0; i < 8; ++i) buf[i] = U[(size_t)(q0 + i) * BB + b];

    #pragma unroll 1
    for (int wi = 0; wi < nwu; ++wi) {
        const int base = q0 + wi * 8;
        WQUAD(0, base) WQUAD(1, base) WQUAD(2, base) WQUAD(3, base)
        WQUAD(4, base) WQUAD(5, base) WQUAD(6, base) WQUAD(7, base)
    }

    // prefetch tf for the head (hidden under the final 32 scan steps)
    float4 tfb[8];
    #pragma unroll
    for (int i = 0; i < 8; ++i) tfb[i] = TF[(size_t)(qout + i) * BB + b];

    float hxr[PL];
    OQUAD(0) OQUAD(1) OQUAD(2) OQUAD(3)
    OQUAD(4) OQUAD(5) OQUAD(6) OQUAD(7)

    // ---------------- intensity head on own 32 hx values ----------------
    float tt[PL];
    #pragma unroll
    for (int i = 0; i < 8; ++i) {
        tt[i*4+0] = tfb[i].x; tt[i*4+1] = tfb[i].y;
        tt[i*4+2] = tfb[i].z; tt[i*4+3] = tfb[i].w;
    }
    #pragma unroll
    for (int ch = 0; ch < 2; ++ch) {          // 2 chunks of 16 t (reg pressure)
        float s[16];
        #pragma unroll
        for (int k = 0; k < 16; ++k) s[k] = 0.0f;
        for (int j = 0; j < NBB; ++j) {
            const float4 c = cb[j];
            #pragma unroll
            for (int k = 0; k < 16; ++k) {
                const float hx = hxr[ch*16 + k];
                float alpha = fmaf(hx, c.x, c.z);
                float beta  = fmaf(hx, c.y, c.w);
                s[k] += fmaxf(fmaf(alpha, tt[ch*16 + k], beta), 0.0f);
            }
        }
        #pragma unroll
        for (int k = 0; k < 16; ++k) {
            float vv = s[k];
            float as = fabsf(vv);
            float e  = __builtin_amdgcn_exp2f(-as * 1.4426950408889634f);
            float lg = __builtin_amdgcn_logf(1.0f + e) * 0.6931471805599453f;
            out_l[(size_t)(tb0 + ch*16 + k) * BB + b] = fmaxf(vv, 0.0f) + lg;
        }
    }
}

// ---------------------------------------------------------------------------
extern "C" void kernel_launch(void* const* d_in, const int* in_sizes, int n_in,
                              void* d_out, int out_size, void* d_ws, size_t ws_size,
                              hipStream_t stream) {
    const float* X     = (const float*)d_in[0];
    const float* hx0   = (const float*)d_in[1];
    const float* W_ih  = (const float*)d_in[2];
    const float* b_ih  = (const float*)d_in[3];
    const float* W_hh  = (const float*)d_in[4];
    const float* b_hh  = (const float*)d_in[5];
    const float* W_h2p = (const float*)d_in[6];
    const float* b_h2p = (const float*)d_in[7];

    float* out_h = (float*)d_out;                 // hidden_states (S,B,1) [t][b]
    float* out_l = out_h + (size_t)SS * BB;       // intensity     (S,B)   [t][b]
    float* u4  = (float*)d_ws;                    // u'' t4-layout, 2 MiB
    float* tf4 = u4 + (size_t)BB * SS;            // X[:,:,1] t4-layout, 2 MiB

    k_proj<<<2048, 256, 0, stream>>>(X, W_ih, b_ih, b_hh, W_hh, u4, tf4);
    k_scanlam<<<NP, 256, 0, stream>>>(u4, tf4, hx0, W_hh, W_h2p, b_h2p,
                                      out_h, out_l);
}

// Round 8
// 38.522 us; speedup vs baseline: 6.6363x; 1.2735x over previous
//
#include <hip/hip_runtime.h>

#define BB 256
#define SS 2048
#define FF 64
#define NBB 32

#define PL 16             // output timesteps per scan partition
#define NP (SS/PL)        // 128 partitions
#define TOTQ 28           // quads per unclamped partition = 112 steps (96 warm)

// 2*log2(e): folded into u so the scan's tanh needs only exp2 on the chain
#define TWO_OVER_LN2 2.885390081777927f

// ---------------------------------------------------------------------------
// K1: u4[t4] = 2log2e*(dot(X[b,t,:],W_ih)+b_ih+b_hh) + 2log2e*W_hh
//     tf4[t4] = X[b,t,1]
// t4 layout: elem (b,t) at ((t>>2)*BB + b)*4 + (t&3); scan reads float4 quads.
// Each 16-lane group does 4 rows (one t-quad) per iteration -> 4 loads in
// flight per lane and ONE packed float4 store each to u4/tf4 (lane 0).
// ---------------------------------------------------------------------------
__global__ __launch_bounds__(256) void k_proj(
    const float* __restrict__ X, const float* __restrict__ W_ih,
    const float* __restrict__ b_ih, const float* __restrict__ b_hh,
    const float* __restrict__ W_hh,
    float* __restrict__ u4, float* __restrict__ tf4)
{
    const int l = threadIdx.x & 15;
    const int group = (blockIdx.x * 256 + threadIdx.x) >> 4;   // 0..32767
    const float4 w = reinterpret_cast<const float4*>(W_ih)[l];
    const float bias = b_ih[0] + b_hh[0];
    const float wp = W_hh[0] * TWO_OVER_LN2;
    #pragma unroll 1
    for (int it = 0; it < 4; ++it) {
        const int r0 = (it * 32768 + group) * 4;   // 4 rows: same b, one t-quad
        float4 v[4];
        #pragma unroll
        for (int k = 0; k < 4; ++k)
            v[k] = reinterpret_cast<const float4*>(X + (size_t)(r0 + k) * FF)[l];
        float pq[4];
        #pragma unroll
        for (int k = 0; k < 4; ++k) {
            float p = v[k].x*w.x + v[k].y*w.y + v[k].z*w.z + v[k].w*w.w;
            p += __shfl_xor(p, 1);
            p += __shfl_xor(p, 2);
            p += __shfl_xor(p, 4);
            p += __shfl_xor(p, 8);
            pq[k] = TWO_OVER_LN2 * (p + bias) + wp;
        }
        if (l == 0) {
            const int b = r0 >> 11;                 // r0 / SS
            const int t = r0 & (SS - 1);            // multiple of 4
            const size_t qi = (size_t)(t >> 2) * BB + b;
            reinterpret_cast<float4*>(u4)[qi]  = make_float4(pq[0], pq[1], pq[2], pq[3]);
            reinterpret_cast<float4*>(tf4)[qi] = make_float4(v[0].y, v[1].y, v[2].y, v[3].y);
        }
    }
}

// ---------------------------------------------------------------------------
// K2: fused speculative scan + intensity head. block = partition p (128),
// thread = batch b. 112 steps/partition (96 warm-up: expected residual
// ~e^-190, tail-risk ~1e-15 across 8192 windows; bf16 floor is 0.0625).
// Ping-pong A/B 4-quad register buffers (all-static indexing, no scratch),
// uniform scalar branches only. Output group stashes hx in 16 registers,
// then the same thread runs the 32-basis head on them — no handoff.
// ---------------------------------------------------------------------------
#define SSTEP(c) { \
    float z_ = fmaf(m2w, r, (c)); \
    r = __builtin_amdgcn_rcpf(__builtin_amdgcn_exp2f(z_) + 1.0f); }

#define WARM(N) { \
    SSTEP(N[0].x) SSTEP(N[0].y) SSTEP(N[0].z) SSTEP(N[0].w) \
    SSTEP(N[1].x) SSTEP(N[1].y) SSTEP(N[1].z) SSTEP(N[1].w) \
    SSTEP(N[2].x) SSTEP(N[2].y) SSTEP(N[2].z) SSTEP(N[2].w) \
    SSTEP(N[3].x) SSTEP(N[3].y) SSTEP(N[3].z) SSTEP(N[3].w) }

#define REFILL(N, grp) { \
    _Pragma("unroll") \
    for (int i_ = 0; i_ < 4; ++i_) { \
        int qn_ = q0 + (grp)*4 + i_; if (qn_ > q1-1) qn_ = q1-1; \
        N[i_] = U[(size_t)qn_ * BB + b]; } }

#define OUTG(N) { \
    _Pragma("unroll") \
    for (int i_ = 0; i_ < 4; ++i_) { \
        SSTEP(N[i_].x) hxr[i_*4+0] = fmaf(-2.0f, r, 1.0f); \
        SSTEP(N[i_].y) hxr[i_*4+1] = fmaf(-2.0f, r, 1.0f); \
        SSTEP(N[i_].z) hxr[i_*4+2] = fmaf(-2.0f, r, 1.0f); \
        SSTEP(N[i_].w) hxr[i_*4+3] = fmaf(-2.0f, r, 1.0f); } }

__global__ __launch_bounds__(256) void k_scanlam(
    const float* __restrict__ u4, const float* __restrict__ tf4,
    const float* __restrict__ hx0, const float* __restrict__ W_hh,
    const float* __restrict__ W_h2p, const float* __restrict__ b_h2p,
    float* __restrict__ out_h, float* __restrict__ out_l)
{
    __shared__ float4 cb[NBB];
    if (threadIdx.x < NBB) {
        int j = threadIdx.x;
        cb[j] = make_float4(W_h2p[2*j], W_h2p[2*j+1], b_h2p[2*j], b_h2p[2*j+1]);
    }
    __syncthreads();

    const int b = threadIdx.x;
    const int p = blockIdx.x;
    const float m2w = -2.0f * (W_hh[0] * TWO_OVER_LN2);

    const float4* U  = reinterpret_cast<const float4*>(u4);
    const float4* TF = reinterpret_cast<const float4*>(tf4);

    const int q1   = (p + 1) * 4;          // exclusive end quad
    const int qout = q1 - 4;               // 4 output quads (16 t)
    int q0 = q1 - TOTQ;
    float r;
    if (q0 <= 0) { q0 = 0; r = 0.5f * (1.0f - hx0[b]); }   // exact start
    else         { r = 0.5f; }                              // neutral (hx=0)
    const int G   = (q1 - q0) >> 2;        // 4-quad groups: 1..7
    const int tb0 = p * PL;

    // tf prefetch for the head (hidden under the whole scan)
    float4 tfb0 = TF[(size_t)(qout+0)*BB + b];
    float4 tfb1 = TF[(size_t)(qout+1)*BB + b];
    float4 tfb2 = TF[(size_t)(qout+2)*BB + b];
    float4 tfb3 = TF[(size_t)(qout+3)*BB + b];

    float4 bufA[4], bufB[4];
    REFILL(bufA, 0)
    REFILL(bufB, 1)

    float hxr[PL];
    int g = 0;
    #pragma unroll 1
    for (;;) {
        if (g == G-1) { OUTG(bufA) break; }
        WARM(bufA) REFILL(bufA, g+2) ++g;
        if (g == G-1) { OUTG(bufB) break; }
        WARM(bufB) REFILL(bufB, g+2) ++g;
    }

    #pragma unroll
    for (int k = 0; k < PL; ++k)
        out_h[(size_t)(tb0 + k) * BB + b] = hxr[k];        // coalesced per t

    // ---------------- intensity head on own 16 hx values ----------------
    float tt[PL];
    tt[0]=tfb0.x; tt[1]=tfb0.y; tt[2]=tfb0.z; tt[3]=tfb0.w;
    tt[4]=tfb1.x; tt[5]=tfb1.y; tt[6]=tfb1.z; tt[7]=tfb1.w;
    tt[8]=tfb2.x; tt[9]=tfb2.y; tt[10]=tfb2.z; tt[11]=tfb2.w;
    tt[12]=tfb3.x; tt[13]=tfb3.y; tt[14]=tfb3.z; tt[15]=tfb3.w;

    float s[PL];
    #pragma unroll
    for (int k = 0; k < PL; ++k) s[k] = 0.0f;
    for (int j = 0; j < NBB; ++j) {
        const float4 c = cb[j];               // uniform LDS broadcast
        #pragma unroll
        for (int k = 0; k < PL; ++k) {
            float alpha = fmaf(hxr[k], c.x, c.z);
            float beta  = fmaf(hxr[k], c.y, c.w);
            s[k] += fmaxf(fmaf(alpha, tt[k], beta), 0.0f);
        }
    }
    #pragma unroll
    for (int k = 0; k < PL; ++k) {
        float vv = s[k];
        float as = fabsf(vv);
        float e  = __builtin_amdgcn_exp2f(-as * 1.4426950408889634f);
        float lg = __builtin_amdgcn_logf(1.0f + e) * 0.6931471805599453f;
        out_l[(size_t)(tb0 + k) * BB + b] = fmaxf(vv, 0.0f) + lg;
    }
}

// ---------------------------------------------------------------------------
extern "C" void kernel_launch(void* const* d_in, const int* in_sizes, int n_in,
                              void* d_out, int out_size, void* d_ws, size_t ws_size,
                              hipStream_t stream) {
    const float* X     = (const float*)d_in[0];
    const float* hx0   = (const float*)d_in[1];
    const float* W_ih  = (const float*)d_in[2];
    const float* b_ih  = (const float*)d_in[3];
    const float* W_hh  = (const float*)d_in[4];
    const float* b_hh  = (const float*)d_in[5];
    const float* W_h2p = (const float*)d_in[6];
    const float* b_h2p = (const float*)d_in[7];

    float* out_h = (float*)d_out;                 // hidden_states (S,B,1) [t][b]
    float* out_l = out_h + (size_t)SS * BB;       // intensity     (S,B)   [t][b]
    float* u4  = (float*)d_ws;                    // u'' t4-layout, 2 MiB
    float* tf4 = u4 + (size_t)BB * SS;            // X[:,:,1] t4-layout, 2 MiB

    k_proj<<<2048, 256, 0, stream>>>(X, W_ih, b_ih, b_hh, W_hh, u4, tf4);
    k_scanlam<<<NP, 256, 0, stream>>>(u4, tf4, hx0, W_hh, W_h2p, b_h2p,
                                      out_h, out_l);
}

// Round 9
// 34.141 us; speedup vs baseline: 7.4879x; 1.1283x over previous
//
#include <hip/hip_runtime.h>

#define BB 256
#define SS 2048
#define FF 64
#define NBB 32

#define TPB 512            // threads per block (8 waves)
#define MT 2               // output timesteps per thread
#define OT (TPB*MT)        // 1024 output t per block
#define WUP 96             // speculative warm-up steps (proven in rounds 5-8)
#define ROWS (OT+WUP)      // 1120 u rows in LDS
#define NCHUNK (SS/OT)     // 2 t-chunks
#define NGRP (TPB/16)      // 32 16-lane groups
#define RPG (ROWS/NGRP)    // 35 rows per group
#define NF2 (ROWS/2)       // 560 float2 in u_lds

// 2*log2(e): folded into u so the chain needs only exp2
#define TWO_OVER_LN2 2.885390081777927f

// ---------------------------------------------------------------------------
// ONE kernel. block = (batch b, t-chunk of 1024 outputs). No cross-block sync.
//  phase 1: cooperative projection of 1120 rows of X into LDS u (+ tf).
//           u never round-trips HBM; X duplication only 1.09x (warm-up).
//  phase 2: thread j = private speculative chain: 96 warm steps (LDS float2
//           reads, 4-deep static rotating prefetch) -> 2 output steps ->
//           32-basis intensity head in-register -> 4 scattered dword stores.
// Chunk-0 threads with t0 < WUP start EXACT from hx0 (per-step predicate
// skips pre-sequence steps). XCD swizzle: 32 consecutive b per XCD so the
// [t][b] output lines aggregate within one XCD's L2.
// ---------------------------------------------------------------------------

#define CSTEP_P(uu, kk) { \
    float z_ = fmaf(m2w, r, (uu)); \
    float rn_ = __builtin_amdgcn_rcpf(__builtin_amdgcn_exp2f(z_) + 1.0f); \
    r = ((kk) >= K0) ? rn_ : r; }

#define CSTEP_N(uu, kk) { \
    float z_ = fmaf(m2w, r, (uu)); \
    r = __builtin_amdgcn_rcpf(__builtin_amdgcn_exp2f(z_) + 1.0f); }

// 12 groups x 8 steps; each float2 pfX used then refilled 8 steps ahead
// (240cy of chain > ~120cy LDS latency). All indices static per register.
#define WARMLOOP(CS) \
    _Pragma("unroll 1") \
    for (int grp = 0; grp < WUP/8; ++grp) { \
        const int kb = grp * 8; \
        const int rb = j + grp*4 + 4; \
        { const float2 c_ = pf0; CS(c_.x, kb+0) CS(c_.y, kb+1) \
          int ri_ = rb + 0; if (ri_ > NF2-1) ri_ = NF2-1; pf0 = U2[ri_]; } \
        { const float2 c_ = pf1; CS(c_.x, kb+2) CS(c_.y, kb+3) \
          int ri_ = rb + 1; if (ri_ > NF2-1) ri_ = NF2-1; pf1 = U2[ri_]; } \
        { const float2 c_ = pf2; CS(c_.x, kb+4) CS(c_.y, kb+5) \
          int ri_ = rb + 2; if (ri_ > NF2-1) ri_ = NF2-1; pf2 = U2[ri_]; } \
        { const float2 c_ = pf3; CS(c_.x, kb+6) CS(c_.y, kb+7) \
          int ri_ = rb + 3; if (ri_ > NF2-1) ri_ = NF2-1; pf3 = U2[ri_]; } \
    }

__global__ __launch_bounds__(TPB) void k_one(
    const float* __restrict__ X, const float* __restrict__ hx0,
    const float* __restrict__ W_ih, const float* __restrict__ b_ih,
    const float* __restrict__ W_hh, const float* __restrict__ b_hh,
    const float* __restrict__ W_h2p, const float* __restrict__ b_h2p,
    float* __restrict__ out_h, float* __restrict__ out_l)
{
    __shared__ __align__(16) float u_lds[ROWS];
    __shared__ __align__(16) float tf_lds[OT];
    __shared__ float4 cb[NBB];

    // block decode with XCD swizzle: b in [xcd*32, xcd*32+32), 2 chunks each
    const int bid   = blockIdx.x;
    const int xcd   = bid & 7;
    const int qq    = bid >> 3;              // 0..63
    const int b     = xcd * 32 + (qq & 31);
    const int chunk = qq >> 5;               // 0..1
    const int T0    = chunk * OT;

    if (threadIdx.x < NBB) {
        int jj = threadIdx.x;
        cb[jj] = make_float4(W_h2p[2*jj], W_h2p[2*jj+1], b_h2p[2*jj], b_h2p[2*jj+1]);
    }

    const float wp  = W_hh[0] * TWO_OVER_LN2;
    const float m2w = -2.0f * wp;

    // ---------------- phase 1: projection into LDS ----------------
    {
        const int l = threadIdx.x & 15;
        const int g = threadIdx.x >> 4;              // 0..31
        const float4 w = reinterpret_cast<const float4*>(W_ih)[l];
        const float bias = b_ih[0] + b_hh[0];
        const float* Xb = X + (size_t)b * SS * FF;
        #pragma unroll 5
        for (int it = 0; it < RPG; ++it) {
            const int i = g + it * NGRP;             // LDS row
            const int t = T0 - WUP + i;              // global timestep
            float pacc = 0.0f, vy = 0.0f;
            if (t >= 0) {                            // group-uniform predicate
                const float4 v = reinterpret_cast<const float4*>(
                    Xb + (size_t)t * FF)[l];
                pacc = v.x*w.x + v.y*w.y + v.z*w.z + v.w*w.w;
                vy = v.y;
            }
            pacc += __shfl_xor(pacc, 1);
            pacc += __shfl_xor(pacc, 2);
            pacc += __shfl_xor(pacc, 4);
            pacc += __shfl_xor(pacc, 8);
            if (l == 0) {
                u_lds[i] = (t >= 0) ? (TWO_OVER_LN2 * (pacc + bias) + wp) : 0.0f;
                if (i >= WUP) tf_lds[i - WUP] = vy;  // X[b,t,1], t>=0 always here
            }
        }
    }
    __syncthreads();

    // ---------------- phase 2: private speculative chain ----------------
    const int j  = threadIdx.x;
    const int t0 = j * MT;                           // local output t (even)

    float r; int K0;
    if (chunk == 0 && t0 < WUP) { r = 0.5f * (1.0f - hx0[b]); K0 = WUP - t0; }
    else                        { r = 0.5f;          K0 = 0; }

    const float2* U2 = reinterpret_cast<const float2*>(u_lds);
    float2 pf0 = U2[j], pf1 = U2[j+1], pf2 = U2[j+2], pf3 = U2[j+3];

    if (chunk == 0) { WARMLOOP(CSTEP_P) }            // uniform branch per block
    else            { WARMLOOP(CSTEP_N) }

    // after the loop pf0 = u[t0+96], u[t0+97] — the two output steps
    float hxa, hxb;
    { float z = fmaf(m2w, r, pf0.x);
      r = __builtin_amdgcn_rcpf(__builtin_amdgcn_exp2f(z) + 1.0f);
      hxa = fmaf(-2.0f, r, 1.0f); }
    { float z = fmaf(m2w, r, pf0.y);
      r = __builtin_amdgcn_rcpf(__builtin_amdgcn_exp2f(z) + 1.0f);
      hxb = fmaf(-2.0f, r, 1.0f); }

    // ---------------- intensity head, in-register ----------------
    const float2 ttv = reinterpret_cast<const float2*>(tf_lds)[j];
    float s0 = 0.0f, s1 = 0.0f;
    #pragma unroll 8
    for (int jj = 0; jj < NBB; ++jj) {
        const float4 c = cb[jj];                     // uniform LDS broadcast
        s0 += fmaxf(fmaf(fmaf(hxa, c.x, c.z), ttv.x, fmaf(hxa, c.y, c.w)), 0.0f);
        s1 += fmaxf(fmaf(fmaf(hxb, c.x, c.z), ttv.y, fmaf(hxb, c.y, c.w)), 0.0f);
    }

    const size_t o0 = (size_t)(T0 + t0) * BB + b;
    out_h[o0]      = hxa;
    out_h[o0 + BB] = hxb;
    { float as = fabsf(s0);
      float e  = __builtin_amdgcn_exp2f(-as * 1.4426950408889634f);
      float lg = __builtin_amdgcn_logf(1.0f + e) * 0.6931471805599453f;
      out_l[o0] = fmaxf(s0, 0.0f) + lg; }
    { float as = fabsf(s1);
      float e  = __builtin_amdgcn_exp2f(-as * 1.4426950408889634f);
      float lg = __builtin_amdgcn_logf(1.0f + e) * 0.6931471805599453f;
      out_l[o0 + BB] = fmaxf(s1, 0.0f) + lg; }
}

// ---------------------------------------------------------------------------
extern "C" void kernel_launch(void* const* d_in, const int* in_sizes, int n_in,
                              void* d_out, int out_size, void* d_ws, size_t ws_size,
                              hipStream_t stream) {
    const float* X     = (const float*)d_in[0];
    const float* hx0   = (const float*)d_in[1];
    const float* W_ih  = (const float*)d_in[2];
    const float* b_ih  = (const float*)d_in[3];
    const float* W_hh  = (const float*)d_in[4];
    const float* b_hh  = (const float*)d_in[5];
    const float* W_h2p = (const float*)d_in[6];
    const float* b_h2p = (const float*)d_in[7];

    float* out_h = (float*)d_out;                 // hidden_states (S,B,1) [t][b]
    float* out_l = out_h + (size_t)SS * BB;       // intensity     (S,B)   [t][b]

    k_one<<<NCHUNK * BB, TPB, 0, stream>>>(X, hx0, W_ih, b_ih, W_hh, b_hh,
                                           W_h2p, b_h2p, out_h, out_l);
}